// Round 1
// baseline (326.709 us; speedup 1.0000x reference)
//
#include <hip/hip_runtime.h>
#include <stdint.h>

// Problem constants
#define Bb 2
#define Tt 2048
#define DMm 1024
#define Hh 16
#define HDd 64
#define Mrows (Bb*Tt)          // 4096

typedef __attribute__((ext_vector_type(8))) __bf16 bf16x8;
typedef __attribute__((ext_vector_type(4))) __bf16 bf16x4;
typedef __attribute__((ext_vector_type(4))) float  f32x4;

#define GLD16(gp, lp) __builtin_amdgcn_global_load_lds( \
    (const __attribute__((address_space(1))) unsigned int*)(gp), \
    (__attribute__((address_space(3))) unsigned int*)(lp), 16, 0, 0)

// ---------------- cast fp32 -> bf16 (vectorized) ----------------
__global__ __launch_bounds__(256)
void cast_k(const float* __restrict__ in, __bf16* __restrict__ out, int n4) {
  int i = blockIdx.x * 256 + threadIdx.x;
  if (i >= n4) return;
  float4 v = ((const float4*)in)[i];
  bf16x4 o;
  o[0] = (__bf16)v.x; o[1] = (__bf16)v.y; o[2] = (__bf16)v.z; o[3] = (__bf16)v.w;
  ((bf16x4*)out)[i] = o;
}

// ---------------- GEMM: C[M][N] = A[M][K] * B[N][K]^T, bf16 in, fp32 out ----
// 128x128 tile, BK=32, 256 threads = 4 waves (2x2), each wave 64x64 (4x4 frags)
__global__ __launch_bounds__(256)
void gemm_bt(const __bf16* __restrict__ A, const __bf16* __restrict__ Bm,
             float* __restrict__ C, int M, int N, int K) {
  __shared__ __bf16 As[128 * 32];
  __shared__ __bf16 Bs[128 * 32];
  const int tid  = threadIdx.x;
  const int lane = tid & 63, wid = tid >> 6;
  const int l4 = lane & 15, lhi = lane >> 4;
  const int rowBase = blockIdx.y * 128, colBase = blockIdx.x * 128;
  const int wh = wid >> 1, ww = wid & 1;

  f32x4 acc[4][4] = {};

  // staging map: element off e = issue*2048 + wid*512 + lane*8 ; row=e>>5, col=e&31
  const int e0 = wid * 512 + lane * 8;
  const int r0 = e0 >> 5, c0 = e0 & 31;
  const __bf16* a0 = A  + (size_t)(rowBase + r0)      * K + c0;
  const __bf16* a1 = A  + (size_t)(rowBase + r0 + 64) * K + c0;
  const __bf16* b0 = Bm + (size_t)(colBase + r0)      * K + c0;
  const __bf16* b1 = Bm + (size_t)(colBase + r0 + 64) * K + c0;

  for (int k0 = 0; k0 < K; k0 += 32) {
    __syncthreads();
    GLD16(a0 + k0, &As[wid * 512]);
    GLD16(a1 + k0, &As[2048 + wid * 512]);
    GLD16(b0 + k0, &Bs[wid * 512]);
    GLD16(b1 + k0, &Bs[2048 + wid * 512]);
    __syncthreads();   // compiler emits vmcnt(0) drain before s_barrier

    bf16x8 af[4], bfr[4];
#pragma unroll
    for (int i = 0; i < 4; i++) {
      af[i]  = *(const bf16x8*)&As[(wh * 64 + i * 16 + l4) * 32 + lhi * 8];
      bfr[i] = *(const bf16x8*)&Bs[(ww * 64 + i * 16 + l4) * 32 + lhi * 8];
    }
#pragma unroll
    for (int i = 0; i < 4; i++)
#pragma unroll
      for (int j = 0; j < 4; j++)
        acc[i][j] = __builtin_amdgcn_mfma_f32_16x16x32_bf16(af[i], bfr[j], acc[i][j], 0, 0, 0);
  }

  // C/D layout: col = lane&15, row = (lane>>4)*4 + reg
#pragma unroll
  for (int i = 0; i < 4; i++) {
    int R = rowBase + wh * 64 + i * 16 + lhi * 4;
#pragma unroll
    for (int j = 0; j < 4; j++) {
      int Cc = colBase + ww * 64 + j * 16 + l4;
      float* cp = C + (size_t)R * N + Cc;
#pragma unroll
      for (int q = 0; q < 4; q++) cp[(size_t)q * N] = acc[i][j][q];
    }
  }
}

// ---------------- RoPE + scatter to Q/K [B,H,T,64] bf16, V^T [B,H,64,T] -----
__global__ __launch_bounds__(256)
void rope_k(const float* __restrict__ qkv, const float* __restrict__ cosb,
            const float* __restrict__ sinb,
            __bf16* __restrict__ Q, __bf16* __restrict__ K, __bf16* __restrict__ Vt) {
  const int bh = blockIdx.y;           // b*16 + h
  const int b = bh >> 4, h = bh & 15;
  const int t0 = blockIdx.x * 64;
  __shared__ float Vl[64][65];
  const int tid = threadIdx.x;
  const int d = tid & 63;
  const int tl0 = tid >> 6;            // 4 t-rows per iteration

  for (int it = 0; it < 16; ++it) {
    int tl = it * 4 + tl0;
    int t = t0 + tl;
    const float* row = qkv + (size_t)(b * Tt + t) * 3072 + h * 64;
    float q  = row[d],        qp = row[d ^ 32];
    float k  = row[1024 + d], kp = row[1024 + (d ^ 32)];
    float v  = row[2048 + d];
    float c  = cosb[t * 64 + d], sn = sinb[t * 64 + d];
    float sg = (d < 32) ? -1.f : 1.f;
    float qr = q * c + sg * qp * sn;
    float kr = k * c + sg * kp * sn;
    size_t o = (size_t)bh * Tt * 64 + (size_t)t * 64 + d;
    Q[o] = (__bf16)(qr * 0.125f);      // fold softmax scale into Q
    K[o] = (__bf16)kr;
    Vl[tl][d] = v;
  }
  __syncthreads();
  for (int it = 0; it < 16; ++it) {
    int dr = it * 4 + tl0;
    Vt[(size_t)bh * 64 * Tt + (size_t)dr * Tt + t0 + d] = (__bf16)Vl[d][dr];
  }
}

// ---------------- Flash attention, causal, bf16 MFMA ------------------------
// grid: (T/64, B*H); 256 threads = 4 waves; wave w owns q rows [qt*64+w*16, +16)
__global__ __launch_bounds__(256)
void attn_k(const __bf16* __restrict__ Q, const __bf16* __restrict__ K,
            const __bf16* __restrict__ Vt, __bf16* __restrict__ O) {
  const int bh = blockIdx.y;
  const int b = bh >> 4, h = bh & 15;
  const int tid = threadIdx.x, lane = tid & 63, wid = tid >> 6;
  const int l4 = lane & 15, lhi = lane >> 4;
  const int qrow0 = blockIdx.x * 64 + wid * 16;
  const size_t baseQK = (size_t)bh * Tt * 64;
  const size_t baseVt = (size_t)bh * 64 * Tt;

  __shared__ float Pl[4][16 * 36];     // per-wave P scratch, stride 36 (16B-aligned rows)
  float* Pw = Pl[wid];

  bf16x8 qf[2];
#pragma unroll
  for (int kc = 0; kc < 2; kc++)
    qf[kc] = *(const bf16x8*)(Q + baseQK + (size_t)(qrow0 + l4) * 64 + kc * 32 + lhi * 8);

  f32x4 o[4] = {};
  float m[4], ssum[4];
#pragma unroll
  for (int j = 0; j < 4; j++) { m[j] = -__builtin_inff(); ssum[j] = 0.f; }

  const int qmax = qrow0 + 15;
  for (int kt0 = 0; kt0 <= qmax; kt0 += 32) {
    // S^ = (Q*0.125) K^T : 16q x 32keys
    f32x4 sc[2] = {};
#pragma unroll
    for (int ct = 0; ct < 2; ct++)
#pragma unroll
      for (int kc = 0; kc < 2; kc++) {
        bf16x8 kf = *(const bf16x8*)(K + baseQK + (size_t)(kt0 + ct * 16 + l4) * 64 + kc * 32 + lhi * 8);
        sc[ct] = __builtin_amdgcn_mfma_f32_16x16x32_bf16(qf[kc], kf, sc[ct], 0, 0, 0);
      }

    float sv[2][4];
#pragma unroll
    for (int ct = 0; ct < 2; ct++)
#pragma unroll
      for (int j = 0; j < 4; j++) {
        int kg = kt0 + ct * 16 + l4;
        int qg = qrow0 + lhi * 4 + j;
        sv[ct][j] = (kg <= qg) ? sc[ct][j] : -__builtin_inff();
      }

#pragma unroll
    for (int j = 0; j < 4; j++) {
      float mx = fmaxf(sv[0][j], sv[1][j]);
#pragma unroll
      for (int dd = 1; dd < 16; dd <<= 1) mx = fmaxf(mx, __shfl_xor(mx, dd));
      float nm = fmaxf(m[j], mx);
      float al = __expf(m[j] - nm);
      m[j] = nm;
      float p0 = __expf(sv[0][j] - nm);
      float p1 = __expf(sv[1][j] - nm);
      float rs = p0 + p1;
#pragma unroll
      for (int dd = 1; dd < 16; dd <<= 1) rs += __shfl_xor(rs, dd);
      ssum[j] = ssum[j] * al + rs;
#pragma unroll
      for (int n = 0; n < 4; n++) o[n][j] *= al;
      int r = lhi * 4 + j;
      Pw[r * 36 + l4]      = p0;
      Pw[r * 36 + 16 + l4] = p1;
    }

    // P fragment: lane holds P[l4][lhi*8 + 0..7]  (wave-private LDS, no barrier)
    f32x4 pa = *(const f32x4*)&Pw[l4 * 36 + lhi * 8];
    f32x4 pb = *(const f32x4*)&Pw[l4 * 36 + lhi * 8 + 4];
    bf16x8 pf;
#pragma unroll
    for (int q = 0; q < 4; q++) { pf[q] = (__bf16)pa[q]; pf[4 + q] = (__bf16)pb[q]; }

#pragma unroll
    for (int n = 0; n < 4; n++) {
      bf16x8 vf = *(const bf16x8*)(Vt + baseVt + (size_t)(n * 16 + l4) * Tt + kt0 + lhi * 8);
      o[n] = __builtin_amdgcn_mfma_f32_16x16x32_bf16(pf, vf, o[n], 0, 0, 0);
    }
  }

  // epilogue: O[b][t][h*64+d], normalize by row sums
  float inv[4];
#pragma unroll
  for (int j = 0; j < 4; j++) inv[j] = 1.f / ssum[j];
#pragma unroll
  for (int n = 0; n < 4; n++)
#pragma unroll
    for (int j = 0; j < 4; j++) {
      int qg = qrow0 + lhi * 4 + j;
      int dc = n * 16 + l4;
      O[((size_t)b * Tt + qg) * DMm + h * 64 + dc] = (__bf16)(o[n][j] * inv[j]);
    }
}

// ---------------- launch -----------------------------------------------------
extern "C" void kernel_launch(void* const* d_in, const int* in_sizes, int n_in,
                              void* d_out, int out_size, void* d_ws, size_t ws_size,
                              hipStream_t stream) {
  const float* x     = (const float*)d_in[0];
  const float* cosb  = (const float*)d_in[1];
  const float* sinb  = (const float*)d_in[2];
  const float* wqkv  = (const float*)d_in[3];
  const float* wproj = (const float*)d_in[4];
  float* out = (float*)d_out;

  char* ws = (char*)d_ws;
  __bf16* xb     = (__bf16*)(ws + 0);          //  8 MB  (4096x1024)
  __bf16* wqkvb  = (__bf16*)(ws + 8388608);    //  6 MB  (3072x1024)
  __bf16* wprojb = (__bf16*)(ws + 14680064);   //  2 MB  (1024x1024)
  float*  qkvf   = (float* )(ws + 16777216);   // 48 MB  (4096x3072 fp32)
  __bf16* Qb     = (__bf16*)(ws + 67108864);   //  8 MB  [B,H,T,64]
  __bf16* Kb     = (__bf16*)(ws + 75497472);   //  8 MB  [B,H,T,64]
  __bf16* Vtb    = (__bf16*)(ws + 83886080);   //  8 MB  [B,H,64,T]
  __bf16* attno  = (__bf16*)(ws + 92274688);   //  8 MB  [B,T,1024]

  cast_k<<<4096, 256, 0, stream>>>(x,     xb,     1048576);
  cast_k<<<3072, 256, 0, stream>>>(wqkv,  wqkvb,   786432);
  cast_k<<<1024, 256, 0, stream>>>(wproj, wprojb,  262144);

  dim3 g1(3072 / 128, Mrows / 128);
  gemm_bt<<<g1, 256, 0, stream>>>(xb, wqkvb, qkvf, Mrows, 3072, 1024);

  dim3 gr(Tt / 64, Bb * Hh);
  rope_k<<<gr, 256, 0, stream>>>(qkvf, cosb, sinb, Qb, Kb, Vtb);

  attn_k<<<gr, 256, 0, stream>>>(Qb, Kb, Vtb, attno);

  dim3 g2(DMm / 128, Mrows / 128);
  gemm_bt<<<g2, 256, 0, stream>>>(attno, wprojb, out, Mrows, DMm, 1024);
}

// Round 2
// 214.267 us; speedup vs baseline: 1.5248x; 1.5248x over previous
//
#include <hip/hip_runtime.h>
#include <stdint.h>

// Problem constants
#define Bb 2
#define Tt 2048
#define DMm 1024
#define Hh 16
#define HDd 64
#define Mrows (Bb*Tt)          // 4096

typedef __attribute__((ext_vector_type(8)))  __bf16 bf16x8;
typedef __attribute__((ext_vector_type(4)))  __bf16 bf16x4;
typedef __attribute__((ext_vector_type(4)))  float  f32x4;
typedef __attribute__((ext_vector_type(16))) float  f32x16;
typedef __attribute__((ext_vector_type(4)))  unsigned int u32x4;
typedef __attribute__((ext_vector_type(2)))  unsigned int u32x2;

#define GLD16(gp, lp) __builtin_amdgcn_global_load_lds( \
    (const __attribute__((address_space(1))) unsigned int*)(gp), \
    (__attribute__((address_space(3))) unsigned int*)(lp), 16, 0, 0)

static __device__ __forceinline__ unsigned cvtpk_bf16(float lo, float hi) {
  unsigned r;
  asm("v_cvt_pk_bf16_f32 %0, %1, %2" : "=v"(r) : "v"(lo), "v"(hi));
  return r;
}

// ---------------- cast fp32 -> bf16 (vectorized) ----------------
__global__ __launch_bounds__(256)
void cast_k(const float* __restrict__ in, __bf16* __restrict__ out, int n4) {
  int i = blockIdx.x * 256 + threadIdx.x;
  if (i >= n4) return;
  float4 v = ((const float4*)in)[i];
  bf16x4 o;
  o[0] = (__bf16)v.x; o[1] = (__bf16)v.y; o[2] = (__bf16)v.z; o[3] = (__bf16)v.w;
  ((bf16x4*)out)[i] = o;
}

// ---------------- GEMM: C[M][N] = A[M][K] * B[N][K]^T, bf16 in, fp32 out ----
__global__ __launch_bounds__(256)
void gemm_bt(const __bf16* __restrict__ A, const __bf16* __restrict__ Bm,
             float* __restrict__ C, int M, int N, int K) {
  __shared__ __bf16 As[128 * 32];
  __shared__ __bf16 Bs[128 * 32];
  const int tid  = threadIdx.x;
  const int lane = tid & 63, wid = tid >> 6;
  const int l4 = lane & 15, lhi = lane >> 4;
  const int rowBase = blockIdx.y * 128, colBase = blockIdx.x * 128;
  const int wh = wid >> 1, ww = wid & 1;

  f32x4 acc[4][4] = {};

  const int e0 = wid * 512 + lane * 8;
  const int r0 = e0 >> 5, c0 = e0 & 31;
  const __bf16* a0 = A  + (size_t)(rowBase + r0)      * K + c0;
  const __bf16* a1 = A  + (size_t)(rowBase + r0 + 64) * K + c0;
  const __bf16* b0 = Bm + (size_t)(colBase + r0)      * K + c0;
  const __bf16* b1 = Bm + (size_t)(colBase + r0 + 64) * K + c0;

  for (int k0 = 0; k0 < K; k0 += 32) {
    __syncthreads();
    GLD16(a0 + k0, &As[wid * 512]);
    GLD16(a1 + k0, &As[2048 + wid * 512]);
    GLD16(b0 + k0, &Bs[wid * 512]);
    GLD16(b1 + k0, &Bs[2048 + wid * 512]);
    __syncthreads();

    bf16x8 af[4], bfr[4];
#pragma unroll
    for (int i = 0; i < 4; i++) {
      af[i]  = *(const bf16x8*)&As[(wh * 64 + i * 16 + l4) * 32 + lhi * 8];
      bfr[i] = *(const bf16x8*)&Bs[(ww * 64 + i * 16 + l4) * 32 + lhi * 8];
    }
#pragma unroll
    for (int i = 0; i < 4; i++)
#pragma unroll
      for (int j = 0; j < 4; j++)
        acc[i][j] = __builtin_amdgcn_mfma_f32_16x16x32_bf16(af[i], bfr[j], acc[i][j], 0, 0, 0);
  }

#pragma unroll
  for (int i = 0; i < 4; i++) {
    int R = rowBase + wh * 64 + i * 16 + lhi * 4;
#pragma unroll
    for (int j = 0; j < 4; j++) {
      int Cc = colBase + ww * 64 + j * 16 + l4;
      float* cp = C + (size_t)R * N + Cc;
#pragma unroll
      for (int q = 0; q < 4; q++) cp[(size_t)q * N] = acc[i][j][q];
    }
  }
}

// ---------------- RoPE + scatter to Q/K [B,H,T,64] bf16, V^T [B,H,64,T] -----
__global__ __launch_bounds__(256)
void rope_k(const float* __restrict__ qkv, const float* __restrict__ cosb,
            const float* __restrict__ sinb,
            __bf16* __restrict__ Q, __bf16* __restrict__ K, __bf16* __restrict__ Vt) {
  const int bh = blockIdx.y;           // b*16 + h
  const int b = bh >> 4, h = bh & 15;
  const int t0 = blockIdx.x * 64;
  __shared__ float Vl[64][65];
  const int tid = threadIdx.x;
  const int d = tid & 63;
  const int tl0 = tid >> 6;

  for (int it = 0; it < 16; ++it) {
    int tl = it * 4 + tl0;
    int t = t0 + tl;
    const float* row = qkv + (size_t)(b * Tt + t) * 3072 + h * 64;
    float q  = row[d],        qp = row[d ^ 32];
    float k  = row[1024 + d], kp = row[1024 + (d ^ 32)];
    float v  = row[2048 + d];
    float c  = cosb[t * 64 + d], sn = sinb[t * 64 + d];
    float sg = (d < 32) ? -1.f : 1.f;
    float qr = q * c + sg * qp * sn;
    float kr = k * c + sg * kp * sn;
    size_t o = (size_t)bh * Tt * 64 + (size_t)t * 64 + d;
    Q[o] = (__bf16)(qr * 0.125f);      // fold softmax scale into Q
    K[o] = (__bf16)kr;
    Vl[tl][d] = v;
  }
  __syncthreads();
  for (int it = 0; it < 16; ++it) {
    int dr = it * 4 + tl0;
    Vt[(size_t)bh * 64 * Tt + (size_t)dr * Tt + t0 + d] = (__bf16)Vl[d][dr];
  }
}

// ---------------- Flash attention, swapped QK^T, in-register softmax --------
// grid: (T/64, B*H); 128 threads = 2 waves; wave w owns q rows [qt*64+w*32, +32)
// S^T = K * Q^T via mfma_32x32x16: lane holds S^T[k][q=l&31], k over 16 regs.
__global__ __launch_bounds__(128)
void attn_k(const __bf16* __restrict__ Q, const __bf16* __restrict__ K,
            const __bf16* __restrict__ Vt, __bf16* __restrict__ O) {
  const int bh = blockIdx.y;
  const int b = bh >> 4, h = bh & 15;
  const int tid = threadIdx.x, lane = tid & 63, wid = tid >> 6;
  const int l5 = lane & 31, hi = lane >> 5;
  const int qt = (int)gridDim.x - 1 - (int)blockIdx.x;   // big tiles first
  const int qrow0 = qt * 64 + wid * 32;
  const size_t baseQK = (size_t)bh * Tt * 64;
  const size_t baseVt = (size_t)bh * 64 * Tt;
  const float NEG_INF = -__builtin_inff();

  // Q as B-operand: col q = l5, contraction d = c*16 + hi*8 + j
  bf16x8 qf[4];
#pragma unroll
  for (int c = 0; c < 4; c++)
    qf[c] = *(const bf16x8*)(Q + baseQK + (size_t)(qrow0 + l5) * 64 + c * 16 + hi * 8);

  f32x16 o0 = {}, o1 = {};
  float m = NEG_INF, ssum = 0.f;
  const int qg = qrow0 + l5;           // this lane's q row
  const int qmax = qrow0 + 31;

  for (int kt0 = 0; kt0 <= qmax; kt0 += 32) {
    // K as A-operand: row k = l5, d = c*16 + hi*8 + j
    const __bf16* Kp = K + baseQK + (size_t)(kt0 + l5) * 64 + hi * 8;
    bf16x8 kf0 = *(const bf16x8*)(Kp);
    bf16x8 kf1 = *(const bf16x8*)(Kp + 16);
    bf16x8 kf2 = *(const bf16x8*)(Kp + 32);
    bf16x8 kf3 = *(const bf16x8*)(Kp + 48);
    // V as B-operand: col d = nt*32 + l5, contraction k = kc*16 + hi*8 + j
    bf16x8 vf[2][2];
#pragma unroll
    for (int nt = 0; nt < 2; nt++)
#pragma unroll
      for (int kc = 0; kc < 2; kc++)
        vf[nt][kc] = *(const bf16x8*)(Vt + baseVt + (size_t)(nt * 32 + l5) * Tt
                                      + kt0 + kc * 16 + hi * 8);

    f32x16 s = {};
    s = __builtin_amdgcn_mfma_f32_32x32x16_bf16(kf0, qf[0], s, 0, 0, 0);
    s = __builtin_amdgcn_mfma_f32_32x32x16_bf16(kf1, qf[1], s, 0, 0, 0);
    s = __builtin_amdgcn_mfma_f32_32x32x16_bf16(kf2, qf[2], s, 0, 0, 0);
    s = __builtin_amdgcn_mfma_f32_32x32x16_bf16(kf3, qf[3], s, 0, 0, 0);

    // causal mask, in-lane: reg r -> k = (r&3) + 8*(r>>2) + 4*hi
    float sv[16];
#pragma unroll
    for (int r = 0; r < 16; r++) {
      int kg = kt0 + (r & 3) + 8 * (r >> 2) + 4 * hi;
      sv[r] = (kg <= qg) ? s[r] : NEG_INF;
    }

    float pmax = sv[0];
#pragma unroll
    for (int r = 1; r < 16; r++) pmax = fmaxf(pmax, sv[r]);
    pmax = fmaxf(pmax, __shfl_xor(pmax, 32));

    // defer-max: rescale only when running max grows by > 8
    if (__any(pmax > m + 8.f)) {
      float mn = fmaxf(m, pmax);
      float al = __expf(m - mn);
      m = mn;
      ssum *= al;
      float arow[16];
#pragma unroll
      for (int r = 0; r < 16; r++) arow[r] = __shfl(al, (r & 3) + 8 * (r >> 2) + 4 * hi);
#pragma unroll
      for (int r = 0; r < 16; r++) { o0[r] *= arow[r]; o1[r] *= arow[r]; }
    }

    float p[16], rsl = 0.f;
#pragma unroll
    for (int r = 0; r < 16; r++) { p[r] = __expf(sv[r] - m); rsl += p[r]; }
    ssum += rsl + __shfl_xor(rsl, 32);

    // P -> bf16 A-fragments (row q = l5, k = kc*16 + hi*8 + j) via cvt_pk + permlane32_swap
    bf16x8 pa[2];
#pragma unroll
    for (int kc = 0; kc < 2; kc++) {
      const float* pp = p + kc * 8;
      unsigned X0 = cvtpk_bf16(pp[0], pp[1]);
      unsigned Y0 = cvtpk_bf16(pp[4], pp[5]);
      unsigned X1 = cvtpk_bf16(pp[2], pp[3]);
      unsigned Y1 = cvtpk_bf16(pp[6], pp[7]);
      u32x2 r0 = __builtin_amdgcn_permlane32_swap(X0, Y0, false, false); // w0, w2
      u32x2 r1 = __builtin_amdgcn_permlane32_swap(X1, Y1, false, false); // w1, w3
      u32x4 pw;
      pw[0] = r0[0]; pw[1] = r1[0]; pw[2] = r0[1]; pw[3] = r1[1];
      pa[kc] = __builtin_bit_cast(bf16x8, pw);
    }

    o0 = __builtin_amdgcn_mfma_f32_32x32x16_bf16(pa[0], vf[0][0], o0, 0, 0, 0);
    o0 = __builtin_amdgcn_mfma_f32_32x32x16_bf16(pa[1], vf[0][1], o0, 0, 0, 0);
    o1 = __builtin_amdgcn_mfma_f32_32x32x16_bf16(pa[0], vf[1][0], o1, 0, 0, 0);
    o1 = __builtin_amdgcn_mfma_f32_32x32x16_bf16(pa[1], vf[1][1], o1, 0, 0, 0);
  }

  // epilogue: normalize and store O[b][t][h*64+d]
  float invl = 1.f / ssum;
  float rinv[16];
#pragma unroll
  for (int r = 0; r < 16; r++) rinv[r] = __shfl(invl, (r & 3) + 8 * (r >> 2) + 4 * hi);
#pragma unroll
  for (int r = 0; r < 16; r++) {
    int qg2 = qrow0 + (r & 3) + 8 * (r >> 2) + 4 * hi;
    __bf16* op = O + ((size_t)b * Tt + qg2) * DMm + h * 64 + l5;
    op[0]  = (__bf16)(o0[r] * rinv[r]);
    op[32] = (__bf16)(o1[r] * rinv[r]);
  }
}

// ---------------- launch -----------------------------------------------------
extern "C" void kernel_launch(void* const* d_in, const int* in_sizes, int n_in,
                              void* d_out, int out_size, void* d_ws, size_t ws_size,
                              hipStream_t stream) {
  const float* x     = (const float*)d_in[0];
  const float* cosb  = (const float*)d_in[1];
  const float* sinb  = (const float*)d_in[2];
  const float* wqkv  = (const float*)d_in[3];
  const float* wproj = (const float*)d_in[4];
  float* out = (float*)d_out;

  char* ws = (char*)d_ws;
  __bf16* xb     = (__bf16*)(ws + 0);          //  8 MB  (4096x1024)
  __bf16* wqkvb  = (__bf16*)(ws + 8388608);    //  6 MB  (3072x1024)
  __bf16* wprojb = (__bf16*)(ws + 14680064);   //  2 MB  (1024x1024)
  float*  qkvf   = (float* )(ws + 16777216);   // 48 MB  (4096x3072 fp32)
  __bf16* Qb     = (__bf16*)(ws + 67108864);   //  8 MB  [B,H,T,64]
  __bf16* Kb     = (__bf16*)(ws + 75497472);   //  8 MB  [B,H,T,64]
  __bf16* Vtb    = (__bf16*)(ws + 83886080);   //  8 MB  [B,H,64,T]
  __bf16* attno  = (__bf16*)(ws + 92274688);   //  8 MB  [B,T,1024]

  cast_k<<<4096, 256, 0, stream>>>(x,     xb,     1048576);
  cast_k<<<3072, 256, 0, stream>>>(wqkv,  wqkvb,   786432);
  cast_k<<<1024, 256, 0, stream>>>(wproj, wprojb,  262144);

  dim3 g1(3072 / 128, Mrows / 128);
  gemm_bt<<<g1, 256, 0, stream>>>(xb, wqkvb, qkvf, Mrows, 3072, 1024);

  dim3 gr(Tt / 64, Bb * Hh);
  rope_k<<<gr, 256, 0, stream>>>(qkvf, cosb, sinb, Qb, Kb, Vtb);

  dim3 ga(Tt / 64, Bb * Hh);
  attn_k<<<ga, 128, 0, stream>>>(Qb, Kb, Vtb, attno);

  dim3 g2(DMm / 128, Mrows / 128);
  gemm_bt<<<g2, 256, 0, stream>>>(attno, wprojb, out, Mrows, DMm, 1024);
}

// Round 3
// 178.495 us; speedup vs baseline: 1.8304x; 1.2004x over previous
//
#include <hip/hip_runtime.h>
#include <stdint.h>

// Problem constants
#define Bb 2
#define Tt 2048
#define DMm 1024
#define Hh 16
#define HDd 64
#define Mrows (Bb*Tt)          // 4096

typedef __attribute__((ext_vector_type(8)))  __bf16 bf16x8;
typedef __attribute__((ext_vector_type(4)))  __bf16 bf16x4;
typedef __attribute__((ext_vector_type(4)))  float  f32x4;
typedef __attribute__((ext_vector_type(16))) float  f32x16;
typedef __attribute__((ext_vector_type(4)))  unsigned int u32x4;
typedef __attribute__((ext_vector_type(2)))  unsigned int u32x2;

#define GLD16(gp, lp) __builtin_amdgcn_global_load_lds( \
    (const __attribute__((address_space(1))) unsigned int*)(gp), \
    (__attribute__((address_space(3))) unsigned int*)(lp), 16, 0, 0)

static __device__ __forceinline__ unsigned cvtpk_bf16(float lo, float hi) {
  unsigned r;
  asm("v_cvt_pk_bf16_f32 %0, %1, %2" : "=v"(r) : "v"(lo), "v"(hi));
  return r;
}
static __device__ __forceinline__ float exp2_hw(float x) {
  float r;
  asm("v_exp_f32 %0, %1" : "=v"(r) : "v"(x));
  return r;
}

// ---------------- cast fp32 -> bf16 (vectorized) ----------------
__global__ __launch_bounds__(256)
void cast_k(const float* __restrict__ in, __bf16* __restrict__ out, int n4) {
  int i = blockIdx.x * 256 + threadIdx.x;
  if (i >= n4) return;
  float4 v = ((const float4*)in)[i];
  bf16x4 o;
  o[0] = (__bf16)v.x; o[1] = (__bf16)v.y; o[2] = (__bf16)v.z; o[3] = (__bf16)v.w;
  ((bf16x4*)out)[i] = o;
}

// ---------------- GEMM: C[M][N] = A[M][K] * B[N][K]^T, bf16 in, fp32 out ----
__global__ __launch_bounds__(256)
void gemm_bt(const __bf16* __restrict__ A, const __bf16* __restrict__ Bm,
             float* __restrict__ C, int M, int N, int K) {
  __shared__ __bf16 As[128 * 32];
  __shared__ __bf16 Bs[128 * 32];
  const int tid  = threadIdx.x;
  const int lane = tid & 63, wid = tid >> 6;
  const int l4 = lane & 15, lhi = lane >> 4;
  const int rowBase = blockIdx.y * 128, colBase = blockIdx.x * 128;
  const int wh = wid >> 1, ww = wid & 1;

  f32x4 acc[4][4] = {};

  const int e0 = wid * 512 + lane * 8;
  const int r0 = e0 >> 5, c0 = e0 & 31;
  const __bf16* a0 = A  + (size_t)(rowBase + r0)      * K + c0;
  const __bf16* a1 = A  + (size_t)(rowBase + r0 + 64) * K + c0;
  const __bf16* b0 = Bm + (size_t)(colBase + r0)      * K + c0;
  const __bf16* b1 = Bm + (size_t)(colBase + r0 + 64) * K + c0;

  for (int k0 = 0; k0 < K; k0 += 32) {
    __syncthreads();
    GLD16(a0 + k0, &As[wid * 512]);
    GLD16(a1 + k0, &As[2048 + wid * 512]);
    GLD16(b0 + k0, &Bs[wid * 512]);
    GLD16(b1 + k0, &Bs[2048 + wid * 512]);
    __syncthreads();

    bf16x8 af[4], bfr[4];
#pragma unroll
    for (int i = 0; i < 4; i++) {
      af[i]  = *(const bf16x8*)&As[(wh * 64 + i * 16 + l4) * 32 + lhi * 8];
      bfr[i] = *(const bf16x8*)&Bs[(ww * 64 + i * 16 + l4) * 32 + lhi * 8];
    }
#pragma unroll
    for (int i = 0; i < 4; i++)
#pragma unroll
      for (int j = 0; j < 4; j++)
        acc[i][j] = __builtin_amdgcn_mfma_f32_16x16x32_bf16(af[i], bfr[j], acc[i][j], 0, 0, 0);
  }

#pragma unroll
  for (int i = 0; i < 4; i++) {
    int R = rowBase + wh * 64 + i * 16 + lhi * 4;
#pragma unroll
    for (int j = 0; j < 4; j++) {
      int Cc = colBase + ww * 64 + j * 16 + l4;
      float* cp = C + (size_t)R * N + Cc;
#pragma unroll
      for (int q = 0; q < 4; q++) cp[(size_t)q * N] = acc[i][j][q];
    }
  }
}

// ---------------- RoPE + scatter to Q/K [B,H,T,64] bf16, V^T [B,H,64,T] -----
// Q gets 0.125 * log2(e) folded in (softmax scale + exp2 domain).
__global__ __launch_bounds__(256)
void rope_k(const float* __restrict__ qkv, const float* __restrict__ cosb,
            const float* __restrict__ sinb,
            __bf16* __restrict__ Q, __bf16* __restrict__ K, __bf16* __restrict__ Vt) {
  const int bh = blockIdx.y;           // b*16 + h
  const int b = bh >> 4, h = bh & 15;
  const int t0 = blockIdx.x * 64;
  __shared__ float Vl[64][65];
  const int tid = threadIdx.x;
  const int d = tid & 63;
  const int tl0 = tid >> 6;

  for (int it = 0; it < 16; ++it) {
    int tl = it * 4 + tl0;
    int t = t0 + tl;
    const float* row = qkv + (size_t)(b * Tt + t) * 3072 + h * 64;
    float q  = row[d],        qp = row[d ^ 32];
    float k  = row[1024 + d], kp = row[1024 + (d ^ 32)];
    float v  = row[2048 + d];
    float c  = cosb[t * 64 + d], sn = sinb[t * 64 + d];
    float sg = (d < 32) ? -1.f : 1.f;
    float qr = q * c + sg * qp * sn;
    float kr = k * c + sg * kp * sn;
    size_t o = (size_t)bh * Tt * 64 + (size_t)t * 64 + d;
    Q[o] = (__bf16)(qr * 0.18033688f);   // 0.125 * log2(e)
    K[o] = (__bf16)kr;
    Vl[tl][d] = v;
  }
  __syncthreads();
  for (int it = 0; it < 16; ++it) {
    int dr = it * 4 + tl0;
    Vt[(size_t)bh * 64 * Tt + (size_t)dr * Tt + t0 + d] = (__bf16)Vl[d][dr];
  }
}

// ---------------- Flash attention, swapped QK^T, in-register softmax --------
// grid: 1024 blocks 1D; 128 threads = 2 waves; wave w owns 32 q rows.
// bid -> (bh, qt) permuted so the 4 co-resident blocks per CU (bid spacing
// 256 => bh octet 0..3) get complementary qt => equal work per CU.
__global__ __launch_bounds__(128)
void attn_k(const __bf16* __restrict__ Q, const __bf16* __restrict__ K,
            const __bf16* __restrict__ Vt, __bf16* __restrict__ O) {
  const int bid = blockIdx.x;
  const int bh = bid >> 5;
  const int x  = bid & 31;
  const int h4 = bh >> 3;                       // 0..3
  const int xx = (h4 & 2) ? ((x + 16) & 31) : x;
  const int qt = (h4 & 1) ? (31 - xx) : xx;     // per-CU: {x,31-x,x+16,15-x}
  const int b = bh >> 4, h = bh & 15;
  const int tid = threadIdx.x, lane = tid & 63, wid = tid >> 6;
  const int l5 = lane & 31, hi = lane >> 5;
  const int qrow0 = qt * 64 + wid * 32;
  const size_t baseQK = (size_t)bh * Tt * 64;
  const size_t baseVt = (size_t)bh * 64 * Tt;
  const float NEG_INF = -__builtin_inff();

  // Q as B-operand: col q = l5, contraction d = c*16 + hi*8 + j
  bf16x8 qf[4];
#pragma unroll
  for (int c = 0; c < 4; c++)
    qf[c] = *(const bf16x8*)(Q + baseQK + (size_t)(qrow0 + l5) * 64 + c * 16 + hi * 8);

  f32x16 o0 = {}, o1 = {};
  float m = NEG_INF, ssum = 0.f;
  const int qg = qrow0 + l5;           // this lane's q row
  const int qmax = qrow0 + 31;

  const __bf16* Kbase = K  + baseQK + (size_t)l5 * 64 + hi * 8;
  const __bf16* Vbase = Vt + baseVt + (size_t)l5 * Tt + hi * 8;

  // prefetch tile 0
  bf16x8 kc0, kc1, kc2, kc3, vc00, vc01, vc10, vc11;
  {
    const __bf16* Kp = Kbase;
    kc0 = *(const bf16x8*)(Kp);      kc1 = *(const bf16x8*)(Kp + 16);
    kc2 = *(const bf16x8*)(Kp + 32); kc3 = *(const bf16x8*)(Kp + 48);
    vc00 = *(const bf16x8*)(Vbase);
    vc01 = *(const bf16x8*)(Vbase + 16);
    vc10 = *(const bf16x8*)(Vbase + (size_t)32 * Tt);
    vc11 = *(const bf16x8*)(Vbase + (size_t)32 * Tt + 16);
  }

  for (int kt0 = 0; kt0 <= qmax; kt0 += 32) {
    // issue next tile's loads early (register double-buffer)
    bf16x8 kn0 = kc0, kn1 = kc1, kn2 = kc2, kn3 = kc3;
    bf16x8 vn00 = vc00, vn01 = vc01, vn10 = vc10, vn11 = vc11;
    const bool more = (kt0 + 32 <= qmax);
    if (more) {
      const __bf16* Kp = Kbase + (size_t)(kt0 + 32) * 64;
      kn0 = *(const bf16x8*)(Kp);      kn1 = *(const bf16x8*)(Kp + 16);
      kn2 = *(const bf16x8*)(Kp + 32); kn3 = *(const bf16x8*)(Kp + 48);
      const __bf16* Vp = Vbase + kt0 + 32;
      vn00 = *(const bf16x8*)(Vp);
      vn01 = *(const bf16x8*)(Vp + 16);
      vn10 = *(const bf16x8*)(Vp + (size_t)32 * Tt);
      vn11 = *(const bf16x8*)(Vp + (size_t)32 * Tt + 16);
    }

    f32x16 s = {};
    s = __builtin_amdgcn_mfma_f32_32x32x16_bf16(kc0, qf[0], s, 0, 0, 0);
    s = __builtin_amdgcn_mfma_f32_32x32x16_bf16(kc1, qf[1], s, 0, 0, 0);
    s = __builtin_amdgcn_mfma_f32_32x32x16_bf16(kc2, qf[2], s, 0, 0, 0);
    s = __builtin_amdgcn_mfma_f32_32x32x16_bf16(kc3, qf[3], s, 0, 0, 0);

    // causal mask, in-lane: reg r -> k = (r&3) + 8*(r>>2) + 4*hi
    float sv[16];
#pragma unroll
    for (int r = 0; r < 16; r++) {
      int kg = kt0 + (r & 3) + 8 * (r >> 2) + 4 * hi;
      sv[r] = (kg <= qg) ? s[r] : NEG_INF;
    }

    float pmax = sv[0];
#pragma unroll
    for (int r = 1; r < 16; r++) pmax = fmaxf(pmax, sv[r]);
    pmax = fmaxf(pmax, __shfl_xor(pmax, 32));

    // defer-max: rescale only when running max grows by > 11.5 (log2 domain)
    if (__any(pmax > m + 11.5f)) {
      float mn = fmaxf(m, pmax);
      float al = exp2_hw(m - mn);
      m = mn;
      ssum *= al;
      float arow[16];
#pragma unroll
      for (int r = 0; r < 16; r++) arow[r] = __shfl(al, (r & 3) + 8 * (r >> 2) + 4 * hi);
#pragma unroll
      for (int r = 0; r < 16; r++) { o0[r] *= arow[r]; o1[r] *= arow[r]; }
    }

    float p[16], rsl = 0.f;
#pragma unroll
    for (int r = 0; r < 16; r++) { p[r] = exp2_hw(sv[r] - m); rsl += p[r]; }
    ssum += rsl + __shfl_xor(rsl, 32);

    // P -> bf16 A-fragments via cvt_pk + permlane32_swap
    bf16x8 pa[2];
#pragma unroll
    for (int kc = 0; kc < 2; kc++) {
      const float* pp = p + kc * 8;
      unsigned X0 = cvtpk_bf16(pp[0], pp[1]);
      unsigned Y0 = cvtpk_bf16(pp[4], pp[5]);
      unsigned X1 = cvtpk_bf16(pp[2], pp[3]);
      unsigned Y1 = cvtpk_bf16(pp[6], pp[7]);
      u32x2 r0 = __builtin_amdgcn_permlane32_swap(X0, Y0, false, false);
      u32x2 r1 = __builtin_amdgcn_permlane32_swap(X1, Y1, false, false);
      u32x4 pw;
      pw[0] = r0[0]; pw[1] = r1[0]; pw[2] = r0[1]; pw[3] = r1[1];
      pa[kc] = __builtin_bit_cast(bf16x8, pw);
    }

    o0 = __builtin_amdgcn_mfma_f32_32x32x16_bf16(pa[0], vc00, o0, 0, 0, 0);
    o0 = __builtin_amdgcn_mfma_f32_32x32x16_bf16(pa[1], vc01, o0, 0, 0, 0);
    o1 = __builtin_amdgcn_mfma_f32_32x32x16_bf16(pa[0], vc10, o1, 0, 0, 0);
    o1 = __builtin_amdgcn_mfma_f32_32x32x16_bf16(pa[1], vc11, o1, 0, 0, 0);

    kc0 = kn0; kc1 = kn1; kc2 = kn2; kc3 = kn3;
    vc00 = vn00; vc01 = vn01; vc10 = vn10; vc11 = vn11;
  }

  // epilogue: normalize and store O[b][t][h*64+d]
  float invl = 1.f / ssum;
  float rinv[16];
#pragma unroll
  for (int r = 0; r < 16; r++) rinv[r] = __shfl(invl, (r & 3) + 8 * (r >> 2) + 4 * hi);
#pragma unroll
  for (int r = 0; r < 16; r++) {
    int qg2 = qrow0 + (r & 3) + 8 * (r >> 2) + 4 * hi;
    __bf16* op = O + ((size_t)b * Tt + qg2) * DMm + h * 64 + l5;
    op[0]  = (__bf16)(o0[r] * rinv[r]);
    op[32] = (__bf16)(o1[r] * rinv[r]);
  }
}

// ---------------- launch -----------------------------------------------------
extern "C" void kernel_launch(void* const* d_in, const int* in_sizes, int n_in,
                              void* d_out, int out_size, void* d_ws, size_t ws_size,
                              hipStream_t stream) {
  const float* x     = (const float*)d_in[0];
  const float* cosb  = (const float*)d_in[1];
  const float* sinb  = (const float*)d_in[2];
  const float* wqkv  = (const float*)d_in[3];
  const float* wproj = (const float*)d_in[4];
  float* out = (float*)d_out;

  char* ws = (char*)d_ws;
  __bf16* xb     = (__bf16*)(ws + 0);          //  8 MB  (4096x1024)
  __bf16* wqkvb  = (__bf16*)(ws + 8388608);    //  6 MB  (3072x1024)
  __bf16* wprojb = (__bf16*)(ws + 14680064);   //  2 MB  (1024x1024)
  float*  qkvf   = (float* )(ws + 16777216);   // 48 MB  (4096x3072 fp32)
  __bf16* Qb     = (__bf16*)(ws + 67108864);   //  8 MB  [B,H,T,64]
  __bf16* Kb     = (__bf16*)(ws + 75497472);   //  8 MB  [B,H,T,64]
  __bf16* Vtb    = (__bf16*)(ws + 83886080);   //  8 MB  [B,H,64,T]
  __bf16* attno  = (__bf16*)(ws + 92274688);   //  8 MB  [B,T,1024]

  cast_k<<<4096, 256, 0, stream>>>(x,     xb,     1048576);
  cast_k<<<3072, 256, 0, stream>>>(wqkv,  wqkvb,   786432);
  cast_k<<<1024, 256, 0, stream>>>(wproj, wprojb,  262144);

  dim3 g1(3072 / 128, Mrows / 128);
  gemm_bt<<<g1, 256, 0, stream>>>(xb, wqkvb, qkvf, Mrows, 3072, 1024);

  dim3 gr(Tt / 64, Bb * Hh);
  rope_k<<<gr, 256, 0, stream>>>(qkvf, cosb, sinb, Qb, Kb, Vtb);

  attn_k<<<1024, 128, 0, stream>>>(Qb, Kb, Vtb, attno);

  dim3 g2(DMm / 128, Mrows / 128);
  gemm_bt<<<g2, 256, 0, stream>>>(attno, wprojb, out, Mrows, DMm, 1024);
}